// Round 19
// baseline (64.736 us; speedup 1.0000x reference)
//
#include <hip/hip_runtime.h>
#include <hip/hip_bf16.h>

#define BB 16
#define HH 256
#define WW 256
#define CC 16
#define HID 128
#define NPIX (BB*HH*WW)      // 1048576
#define NBLK2 2048           // row-pair blocks
#define NGRP  (NPIX/64)      // 16384 wave-groups (64 px each)

#define PCL_STRIDE 36                  // shorts per px row (32 used + 4 pad)
#define PCL_WAVE2  (128*PCL_STRIDE)    // 4608 shorts per wave (128 px)

typedef __attribute__((ext_vector_type(8))) short s16x8;   // 8 bf16
typedef __attribute__((ext_vector_type(4))) float f32x4;

union V8 { uint4 u; uint2 h[2]; s16x8 s; };

struct Key2 { unsigned a, b; };

__host__ __device__ constexpr unsigned rotl32c(unsigned x, int d) {
    return (x << d) | (x >> (32 - d));
}

// JAX threefry2x32 (20 rounds)
__host__ __device__ constexpr Key2 tf2x32(unsigned k0, unsigned k1, unsigned x0, unsigned x1) {
    const unsigned ks2 = k0 ^ k1 ^ 0x1BD11BDAu;
    const int R[5][4] = {{13,15,26,6},{17,29,16,24},{13,15,26,6},{17,29,16,24},{13,15,26,6}};
    const unsigned ka[5] = {k1, ks2, k0, k1, ks2};
    const unsigned kb[5] = {ks2, k0, k1, ks2, k0};
    x0 += k0; x1 += k1;
    for (int i = 0; i < 5; ++i) {
        for (int j = 0; j < 4; ++j) { x0 += x1; x1 = rotl32c(x1, R[i][j]); x1 ^= x0; }
        x0 += ka[i]; x1 += kb[i] + (unsigned)(i + 1);
    }
    return Key2{x0, x1};
}
constexpr Key2 FK = tf2x32(0u, 42u, 0u, 0u);  // fold_in(key(42), 0)

// pack 2 f32 -> u32 of 2 bf16 (RTNE): lo16 = a, hi16 = b
__device__ inline unsigned pk2(float a, float b) {
    union { __hip_bfloat162 h2; unsigned u; } cv;
    cv.h2 = __float22bfloat162_rn(make_float2(a, b));
    return cv.u;
}
__device__ inline float unpk_lo(unsigned u) { return __uint_as_float(u << 16); }
__device__ inline float unpk_hi(unsigned u) { return __uint_as_float(u & 0xffff0000u); }

// DPP whole-wave shift-by-1
__device__ inline unsigned dpp_up1(unsigned v) {
    return __builtin_amdgcn_update_dpp(0u, v, 0x138, 0xF, 0xF, true);
}
__device__ inline unsigned dpp_down1(unsigned v) {
    return __builtin_amdgcn_update_dpp(0u, v, 0x130, 0xF, 0xF, true);
}
__device__ inline float dpp_up1f(float v) {
    return __uint_as_float(dpp_up1(__float_as_uint(v)));
}
__device__ inline float dpp_down1f(float v) {
    return __uint_as_float(dpp_down1(__float_as_uint(v)));
}

// wave-uniform 64-bit value -> SGPRs (compiler can't prove tid>>6 uniform)
__device__ inline unsigned long long rfl64(unsigned long long v) {
    const unsigned lo = __builtin_amdgcn_readfirstlane((unsigned)v);
    const unsigned hi = __builtin_amdgcn_readfirstlane((unsigned)(v >> 32));
    return ((unsigned long long)hi << 32) | lo;
}

// ---- prep (517 blocks): weights -> fragment-ready bf16 layouts, RNG -> per-group masks ----
// w0bf rows for conv channels (kg>=16) carry the 0.125 sobel scale (exact: power of 2).
__global__ __launch_bounds__(256)
void ca_prep(const float* __restrict__ w0, const float* __restrict__ w1,
             short* __restrict__ w0bf, short* __restrict__ w1bf,
             unsigned long long* __restrict__ kmaskbuf)
{
    const int t = threadIdx.x;
    const int blk = blockIdx.x;
    if (blk < 4) {
        const int row = blk * 256 + t;
        const int l15 = row & 15, g = (row >> 4) & 3, ks = (row >> 6) & 1;
        const int nt = (row >> 7) & 1, p = row >> 8;
        const int n = p * 32 + nt * 16 + l15;
        float v[8];
        #pragma unroll
        for (int jj = 0; jj < 8; ++jj) {
            const int kg = ks * 32 + g * 8 + jj;
            const float sc = (kg >= 16) ? 0.125f : 1.0f;   // fold sobel scale (exact)
            v[jj] = (kg < 48) ? sc * w0[kg * HID + n] : 0.0f;
        }
        uint4 pkv;
        pkv.x = pk2(v[0], v[1]); pkv.y = pk2(v[2], v[3]);
        pkv.z = pk2(v[4], v[5]); pkv.w = pk2(v[6], v[7]);
        *reinterpret_cast<uint4*>(&w0bf[row * 8]) = pkv;
    } else if (blk == 4) {
        const int l15 = t & 15, g = (t >> 4) & 3, p = t >> 6;
        float v[8];
        #pragma unroll
        for (int e = 0; e < 8; ++e) v[e] = w1[(p * 32 + g * 8 + e) * CC + l15];
        uint4 pkv;
        pkv.x = pk2(v[0], v[1]); pkv.y = pk2(v[2], v[3]);
        pkv.z = pk2(v[4], v[5]); pkv.w = pk2(v[6], v[7]);
        *reinterpret_cast<uint4*>(&w1bf[t * 8]) = pkv;
    } else {
        // RNG grid-stride: 512 blocks x 8 iterations x 256 px. uniform>0.5 <=> bits>=0x80000200
        const unsigned base = (unsigned)(blk - 5) * 2048u + (unsigned)t;
        #pragma unroll
        for (int it = 0; it < 8; ++it) {
            const unsigned j = base + (unsigned)it * 256u;
            const Key2 r = tf2x32(FK.a, FK.b, 0u, j);
            const unsigned long long m = __ballot((r.a ^ r.b) >= 0x80000200u);
            if ((t & 63) == 0) kmaskbuf[j >> 6] = m;
        }
    }
}

__global__ __launch_bounds__(256, 4)
void ca_fused(const float* __restrict__ x, const short* __restrict__ w0bf,
              const float* __restrict__ b0, const short* __restrict__ w1bf,
              const unsigned long long* __restrict__ kmaskbuf,
              float* __restrict__ out, float* __restrict__ ch1new,
              unsigned char* __restrict__ prelife)
{
    __shared__ short percL[4 * PCL_WAVE2];   // [wave][128 px][36]; per-half aliased as HP
    __shared__ unsigned slotLp[4][2][16];    // lane-63 packed D/S per px-row
    __shared__ unsigned slotRp[4][2][16];    // lane-0  packed D/S per px-row
    __shared__ float    slotLm[4][2];        // lane-63 M per px-row
    __shared__ float    slotRm[4][2];        // lane-0  M per px-row

    const int tid = threadIdx.x;
    const unsigned bid = blockIdx.x;
    const unsigned lb = (bid & 7u) * 256u + (bid >> 3);   // XCD-chunked swizzle (2048 = 8*256)
    const int hpair = lb & 127;
    const unsigned jbase = lb * 512u;        // = (b*HH + 2*hpair)*WW
    const int wave = tid >> 6, lane = tid & 63;
    const int l15 = lane & 15, g = lane >> 4;

    // ---- stochastic masks precomputed in prep: wave-uniform 8B loads -> SGPRs ----
    const unsigned long long kmask0 = rfl64(kmaskbuf[lb * 8 + 0 * 4 + wave]);
    const unsigned long long kmask1 = rfl64(kmaskbuf[lb * 8 + 1 * 4 + wave]);

    // ---- load 4 rows of own column (R0 = h0-1, R1 = h0, R2 = h1, R3 = h1+1) ----
    const float* pR1 = x + ((size_t)jbase + tid) * CC;
    float4 R0[4], R1[4], R2[4], R3[4];
    #pragma unroll
    for (int q = 0; q < 4; ++q) R1[q] = *reinterpret_cast<const float4*>(pR1 + q * 4);
    #pragma unroll
    for (int q = 0; q < 4; ++q) R2[q] = *reinterpret_cast<const float4*>(pR1 + WW * CC + q * 4);
    if (hpair > 0) {
        #pragma unroll
        for (int q = 0; q < 4; ++q) R0[q] = *reinterpret_cast<const float4*>(pR1 - WW * CC + q * 4);
    } else {
        #pragma unroll
        for (int q = 0; q < 4; ++q) R0[q] = make_float4(0.f, 0.f, 0.f, 0.f);
    }
    if (hpair < 127) {
        #pragma unroll
        for (int q = 0; q < 4; ++q) R3[q] = *reinterpret_cast<const float4*>(pR1 + 2 * WW * CC + q * 4);
    } else {
        #pragma unroll
        for (int q = 0; q < 4; ++q) R3[q] = make_float4(0.f, 0.f, 0.f, 0.f);
    }

    // D/S packed as bf16 pairs (lo=D, hi=S) per channel, per px
    unsigned pkA[16], pkB[16];
    #pragma unroll
    for (int q = 0; q < 4; ++q) {
        const float4 a = R0[q], bb = R1[q], c = R2[q], d = R3[q];
        const float a_[4] = {a.x, a.y, a.z, a.w};
        const float b_[4] = {bb.x, bb.y, bb.z, bb.w};
        const float c_[4] = {c.x, c.y, c.z, c.w};
        const float d_[4] = {d.x, d.y, d.z, d.w};
        #pragma unroll
        for (int e = 0; e < 4; ++e) {
            const int ch = q * 4 + e;
            pkA[ch] = pk2(c_[e] - a_[e], fmaf(2.f, b_[e], a_[e] + c_[e]));   // px1: D,S
            pkB[ch] = pk2(d_[e] - b_[e], fmaf(2.f, c_[e], b_[e] + d_[e]));   // px2: D,S
        }
    }
    const float M1 = fmaxf(fmaxf(R0[0].y, R1[0].y), R2[0].y);
    const float M2 = fmaxf(fmaxf(R1[0].y, R2[0].y), R3[0].y);

    // boundary columns -> LDS slots
    if (lane == 0) {
        #pragma unroll
        for (int c = 0; c < 16; ++c) { slotRp[wave][0][c] = pkA[c]; slotRp[wave][1][c] = pkB[c]; }
        slotRm[wave][0] = M1; slotRm[wave][1] = M2;
    }
    if (lane == 63) {
        #pragma unroll
        for (int c = 0; c < 16; ++c) { slotLp[wave][0][c] = pkA[c]; slotLp[wave][1][c] = pkB[c]; }
        slotLm[wave][0] = M1; slotLm[wave][1] = M2;
    }
    __syncthreads();

    // ---- shuffle-combine (DPP wave shifts) + percL write + prelife, per px ----
    // conv features are UNSCALED (Dl+Dr+2D, Sr-Sl); 0.125 folded into w0bf conv rows.
    #pragma unroll
    for (int rs = 0; rs < 2; ++rs) {
        const unsigned* pk = (rs == 0) ? pkA : pkB;
        float conv[32];
        #pragma unroll
        for (int hf = 0; hf < 2; ++hf) {       // 8 channels at a time (register cap)
            const int c0 = hf * 8;
            unsigned pL[8], pR[8];
            #pragma unroll
            for (int c = 0; c < 8; ++c) {
                pL[c] = dpp_up1(pk[c0 + c]);
                pR[c] = dpp_down1(pk[c0 + c]);
            }
            if (lane == 0) {
                #pragma unroll
                for (int c = 0; c < 8; ++c)
                    pL[c] = (tid == 0) ? 0u : slotLp[wave - 1][rs][c0 + c];
            }
            if (lane == 63) {
                #pragma unroll
                for (int c = 0; c < 8; ++c)
                    pR[c] = (tid == 255) ? 0u : slotRp[wave + 1][rs][c0 + c];
            }
            #pragma unroll
            for (int c = 0; c < 8; ++c) {
                const float Dm = unpk_lo(pk[c0 + c]);
                conv[c0 + c]      = fmaf(2.f, Dm, unpk_lo(pL[c]) + unpk_lo(pR[c])); // k1 (unscaled)
                conv[16 + c0 + c] = unpk_hi(pR[c]) - unpk_hi(pL[c]);                // k2 (unscaled)
            }
        }
        // percL write (wave-local)
        const int base = wave * PCL_WAVE2 + (rs * 64 + lane) * PCL_STRIDE;
        #pragma unroll
        for (int c = 0; c < 8; ++c) {
            uint2 pkv;
            pkv.x = pk2(conv[c*4 + 0], conv[c*4 + 1]);
            pkv.y = pk2(conv[c*4 + 2], conv[c*4 + 3]);
            *reinterpret_cast<uint2*>(&percL[base + c * 4]) = pkv;
        }
        // alive max + prelife
        const float M = (rs == 0) ? M1 : M2;
        float Ml = dpp_up1f(M), Mr = dpp_down1f(M);
        if (lane == 0)  Ml = (tid == 0)   ? -3.0e38f : slotLm[wave - 1][rs];
        if (lane == 63) Mr = (tid == 255) ? -3.0e38f : slotRm[wave + 1][rs];
        const float maxc1 = fmaxf(fmaxf(Ml, M), Mr);
        prelife[jbase + rs * 256 + tid] = (maxc1 > 0.1f) ? (unsigned char)1 : (unsigned char)0;
    }

    const s16x8* w0F = reinterpret_cast<const s16x8*>(w0bf);  // [chunk][lane], 16B/lane
    const s16x8* w1F = reinterpret_cast<const s16x8*>(w1bf);

    // ---- GEMM, one half (64 px = one row chunk) at a time ----
    #pragma unroll
    for (int rs = 0; rs < 2; ++rs) {
        const unsigned pixbase = jbase + rs * 256 + wave * 64;
        const int halfbase = wave * PCL_WAVE2 + rs * 64 * PCL_STRIDE;

        // B-operand fragments: k = [id 0..15 | k1 16..31 | k2 32..47 | pad]
        s16x8 pB0[4], pB1[4];
        #pragma unroll
        for (int mt = 0; mt < 4; ++mt) {
            const int prow = halfbase + (mt * 16 + l15) * PCL_STRIDE;
            V8 f0, f1;
            if (g < 2) {
                const float* xp = &x[(size_t)(pixbase + mt * 16 + l15) * CC + g * 8];
                const float4 va = *reinterpret_cast<const float4*>(xp);
                const float4 vb = *reinterpret_cast<const float4*>(xp + 4);
                f0.u.x = pk2(va.x, va.y); f0.u.y = pk2(va.z, va.w);
                f0.u.z = pk2(vb.x, vb.y); f0.u.w = pk2(vb.z, vb.w);
                f1.h[0] = *reinterpret_cast<const uint2*>(&percL[prow + 16 + g * 8]);
                f1.h[1] = *reinterpret_cast<const uint2*>(&percL[prow + 16 + g * 8 + 4]);
            } else {
                f0.h[0] = *reinterpret_cast<const uint2*>(&percL[prow + (g - 2) * 8]);
                f0.h[1] = *reinterpret_cast<const uint2*>(&percL[prow + (g - 2) * 8 + 4]);
                f1.u = make_uint4(0u, 0u, 0u, 0u);
            }
            pB0[mt] = f0.s;
            pB1[mt] = f1.s;
        }

        __builtin_amdgcn_sched_barrier(0);   // percL reads complete before HP overwrites

        short* HPw = &percL[halfbase];       // [64 px][32 n-of-panel], chunk-XOR swizzle (aliased)
        f32x4 acc2[4];
        #pragma unroll
        for (int mt2 = 0; mt2 < 4; ++mt2) acc2[mt2] = 0.0f;

        __builtin_amdgcn_s_setprio(1);       // favor GEMM-phase waves on the CU scheduler
        #pragma unroll
        for (int p = 0; p < 4; ++p) {
            s16x8 w0f0[2], w0f1[2];
            #pragma unroll
            for (int nt = 0; nt < 2; ++nt) {
                w0f0[nt] = w0F[((p * 2 + nt) * 2 + 0) * 64 + lane];
                w0f1[nt] = w0F[((p * 2 + nt) * 2 + 1) * 64 + lane];
            }
            // bias loads hoisted out of the mt loop (explicit CSE)
            const float4 bvA = *reinterpret_cast<const float4*>(&b0[p*32 + g*4]);
            const float4 bvB = *reinterpret_cast<const float4*>(&b0[p*32 + 16 + g*4]);
            // GEMM1: H^T panel -> relu -> packed b64 HP writes
            #pragma unroll
            for (int mt = 0; mt < 4; ++mt) {
                #pragma unroll
                for (int nt = 0; nt < 2; ++nt) {
                    const float4 bv = (nt == 0) ? bvA : bvB;
                    f32x4 acc = {bv.x, bv.y, bv.z, bv.w};
                    acc = __builtin_amdgcn_mfma_f32_16x16x32_bf16(w0f0[nt], pB0[mt], acc, 0, 0, 0);
                    acc = __builtin_amdgcn_mfma_f32_16x16x32_bf16(w0f1[nt], pB1[mt], acc, 0, 0, 0);
                    uint2 hv;
                    hv.x = pk2(fmaxf(acc[0], 0.f), fmaxf(acc[1], 0.f));
                    hv.y = pk2(fmaxf(acc[2], 0.f), fmaxf(acc[3], 0.f));
                    const int m = mt * 16 + l15;
                    *reinterpret_cast<uint2*>(
                        &HPw[m * 32 + 4 * ((4*nt + g) ^ (l15 & 6))]) = hv;
                }
            }
            // GEMM2 partial: dx^T += w1_panel^T . H^T
            {
                const s16x8 wf = w1F[p * 64 + lane];
                #pragma unroll
                for (int mt2 = 0; mt2 < 4; ++mt2) {
                    const int m = mt2 * 16 + l15;
                    const s16x8 hp = *reinterpret_cast<const s16x8*>(
                        &HPw[m * 32 + 4 * ((2*g) ^ (l15 & 6))]);
                    acc2[mt2] = __builtin_amdgcn_mfma_f32_16x16x32_bf16(wf, hp, acc2[mt2], 0, 0, 0);
                }
            }
        }
        __builtin_amdgcn_s_setprio(0);

        // epilogue for this half: lane holds channels g*4..g*4+3 of px l15+16*mt2
        const unsigned long long kmask = (rs == 0) ? kmask0 : kmask1;
        #pragma unroll
        for (int mt2 = 0; mt2 < 4; ++mt2) {
            const int prel = mt2 * 16 + l15;
            const unsigned pj = pixbase + prel;
            const float kv = ((kmask >> prel) & 1ull) ? 1.0f : 0.0f;
            const float4 x4 = *reinterpret_cast<const float4*>(&x[(size_t)pj * CC + g * 4]);
            float4 v;
            v.x = x4.x + acc2[mt2][0] * kv;
            v.y = x4.y + acc2[mt2][1] * kv;
            v.z = x4.z + acc2[mt2][2] * kv;
            v.w = x4.w + acc2[mt2][3] * kv;
            *reinterpret_cast<float4*>(&out[(size_t)pj * CC + g * 4]) = v;
            if (g == 0) ch1new[pj] = v.y;   // channel 1
        }
    }
}

__global__ __launch_bounds__(256)
void ca_step2(float* __restrict__ out, const float* __restrict__ ch1new,
              const unsigned char* __restrict__ prelife)
{
    const int tid = threadIdx.x;
    const int lane = tid & 63;           // 64 lanes x 4 pixels = 256 w
    const int rowi = tid >> 6;           // 4 rows per block
    const unsigned bid = blockIdx.x;     // 1024 blocks
    const int hq = bid & 63, b = bid >> 6;
    const int h = hq * 4 + rowi;
    const unsigned rowbase = ((unsigned)(b * HH + h)) * WW;
    const int w0 = lane * 4;

    float4 vc = *reinterpret_cast<const float4*>(&ch1new[rowbase + w0]);
    float m0 = vc.x, m1 = vc.y, m2 = vc.z, m3 = vc.w;
    if (h > 0) {
        float4 vu = *reinterpret_cast<const float4*>(&ch1new[rowbase - WW + w0]);
        m0 = fmaxf(m0, vu.x); m1 = fmaxf(m1, vu.y); m2 = fmaxf(m2, vu.z); m3 = fmaxf(m3, vu.w);
    }
    if (h < HH - 1) {
        float4 vd = *reinterpret_cast<const float4*>(&ch1new[rowbase + WW + w0]);
        m0 = fmaxf(m0, vd.x); m1 = fmaxf(m1, vd.y); m2 = fmaxf(m2, vd.z); m3 = fmaxf(m3, vd.w);
    }
    float left  = __shfl_up(m3, 1);   if (lane == 0)  left  = -3.0e38f;
    float right = __shfl_down(m0, 1); if (lane == 63) right = -3.0e38f;

    float mm[4];
    mm[0] = fmaxf(fmaxf(left, m0), m1);
    mm[1] = fmaxf(fmaxf(m0, m1), m2);
    mm[2] = fmaxf(fmaxf(m1, m2), m3);
    mm[3] = fmaxf(fmaxf(m2, m3), right);

    const uchar4 pl = *reinterpret_cast<const uchar4*>(&prelife[rowbase + w0]);
    const unsigned char pla[4] = {pl.x, pl.y, pl.z, pl.w};
    bool dead[4];
    bool anydead = false;
    #pragma unroll
    for (int i = 0; i < 4; ++i) {
        dead[i] = !((pla[i] != 0) && (mm[i] > 0.1f));
        anydead |= dead[i];
    }
    // whole-wave early-out: with typical data nearly all pixels are alive
    if (__ballot(anydead) == 0ull) return;
    #pragma unroll
    for (int i = 0; i < 4; ++i) {
        if (dead[i]) {
            const float4 z = make_float4(0.f, 0.f, 0.f, 0.f);
            float4* o = reinterpret_cast<float4*>(out + (size_t)(rowbase + w0 + i) * CC);
            o[0] = z; o[1] = z; o[2] = z; o[3] = z;
        }
    }
}

extern "C" void kernel_launch(void* const* d_in, const int* in_sizes, int n_in,
                              void* d_out, int out_size, void* d_ws, size_t ws_size,
                              hipStream_t stream) {
    const float* x  = (const float*)d_in[0];
    const float* w0 = (const float*)d_in[1];
    const float* b0 = (const float*)d_in[2];
    const float* w1 = (const float*)d_in[3];
    float* out = (float*)d_out;

    float* ch1new = (float*)d_ws;                                       // NPIX floats (4 MB)
    unsigned char* prelife = (unsigned char*)d_ws + (size_t)NPIX * 4;   // NPIX bytes (1 MB)
    short* w0bf = (short*)((char*)d_ws + 5242880);                      // 16 KB
    short* w1bf = (short*)((char*)d_ws + 5242880 + 16384);              // 4 KB
    unsigned long long* kmaskbuf =
        (unsigned long long*)((char*)d_ws + 5242880 + 20480);           // 128 KB (16384 x 8 B)

    ca_prep<<<dim3(5 + 512), dim3(256), 0, stream>>>(w0, w1, w0bf, w1bf, kmaskbuf);
    ca_fused<<<dim3(NBLK2), dim3(256), 0, stream>>>(x, w0bf, b0, w1bf, kmaskbuf, out, ch1new, prelife);
    ca_step2<<<dim3(NPIX / 1024), dim3(256), 0, stream>>>(out, ch1new, prelife);
}

// Round 20
// 64.096 us; speedup vs baseline: 1.0100x; 1.0100x over previous
//
#include <hip/hip_runtime.h>
#include <hip/hip_bf16.h>

#define BB 16
#define HH 256
#define WW 256
#define CC 16
#define HID 128
#define NPIX (BB*HH*WW)      // 1048576
#define NBLK2 2048           // row-pair blocks
#define NGRP  (NPIX/64)      // 16384 wave-groups (64 px each)

#define PCL_STRIDE 36                  // shorts per px row (32 used + 4 pad)
#define PCL_WAVE2  (128*PCL_STRIDE)    // 4608 shorts per wave (128 px)

typedef __attribute__((ext_vector_type(8))) short s16x8;   // 8 bf16
typedef __attribute__((ext_vector_type(4))) float f32x4;

union V8 { uint4 u; uint2 h[2]; s16x8 s; };

struct Key2 { unsigned a, b; };

__host__ __device__ constexpr unsigned rotl32c(unsigned x, int d) {
    return (x << d) | (x >> (32 - d));
}

// JAX threefry2x32 (20 rounds)
__host__ __device__ constexpr Key2 tf2x32(unsigned k0, unsigned k1, unsigned x0, unsigned x1) {
    const unsigned ks2 = k0 ^ k1 ^ 0x1BD11BDAu;
    const int R[5][4] = {{13,15,26,6},{17,29,16,24},{13,15,26,6},{17,29,16,24},{13,15,26,6}};
    const unsigned ka[5] = {k1, ks2, k0, k1, ks2};
    const unsigned kb[5] = {ks2, k0, k1, ks2, k0};
    x0 += k0; x1 += k1;
    for (int i = 0; i < 5; ++i) {
        for (int j = 0; j < 4; ++j) { x0 += x1; x1 = rotl32c(x1, R[i][j]); x1 ^= x0; }
        x0 += ka[i]; x1 += kb[i] + (unsigned)(i + 1);
    }
    return Key2{x0, x1};
}
constexpr Key2 FK = tf2x32(0u, 42u, 0u, 0u);  // fold_in(key(42), 0)

// pack 2 f32 -> u32 of 2 bf16 (RTNE): lo16 = a, hi16 = b
__device__ inline unsigned pk2(float a, float b) {
    union { __hip_bfloat162 h2; unsigned u; } cv;
    cv.h2 = __float22bfloat162_rn(make_float2(a, b));
    return cv.u;
}
__device__ inline float unpk_lo(unsigned u) { return __uint_as_float(u << 16); }
__device__ inline float unpk_hi(unsigned u) { return __uint_as_float(u & 0xffff0000u); }

// DPP whole-wave shift-by-1
// wave_shr:1 (0x138): dst[l] = src[l-1]  (lane 0 -> 0, patched by caller)
// wave_shl:1 (0x130): dst[l] = src[l+1]  (lane 63 -> 0, patched by caller)
__device__ inline unsigned dpp_up1(unsigned v) {
    return __builtin_amdgcn_update_dpp(0u, v, 0x138, 0xF, 0xF, true);
}
__device__ inline unsigned dpp_down1(unsigned v) {
    return __builtin_amdgcn_update_dpp(0u, v, 0x130, 0xF, 0xF, true);
}
__device__ inline float dpp_up1f(float v) {
    return __uint_as_float(dpp_up1(__float_as_uint(v)));
}
__device__ inline float dpp_down1f(float v) {
    return __uint_as_float(dpp_down1(__float_as_uint(v)));
}

// ---- prep (4101 blocks): weights -> fragment-ready bf16 layouts, RNG -> per-group masks ----
// w0bf rows for conv channels (kg>=16) carry the 0.125 sobel scale (exact: power of 2).
__global__ __launch_bounds__(256)
void ca_prep(const float* __restrict__ w0, const float* __restrict__ w1,
             short* __restrict__ w0bf, short* __restrict__ w1bf,
             unsigned long long* __restrict__ kmaskbuf)
{
    const int t = threadIdx.x;
    const int blk = blockIdx.x;
    if (blk < 4) {
        const int row = blk * 256 + t;
        const int l15 = row & 15, g = (row >> 4) & 3, ks = (row >> 6) & 1;
        const int nt = (row >> 7) & 1, p = row >> 8;
        const int n = p * 32 + nt * 16 + l15;
        float v[8];
        #pragma unroll
        for (int jj = 0; jj < 8; ++jj) {
            const int kg = ks * 32 + g * 8 + jj;
            const float sc = (kg >= 16) ? 0.125f : 1.0f;   // fold sobel scale (exact)
            v[jj] = (kg < 48) ? sc * w0[kg * HID + n] : 0.0f;
        }
        uint4 pkv;
        pkv.x = pk2(v[0], v[1]); pkv.y = pk2(v[2], v[3]);
        pkv.z = pk2(v[4], v[5]); pkv.w = pk2(v[6], v[7]);
        *reinterpret_cast<uint4*>(&w0bf[row * 8]) = pkv;
    } else if (blk == 4) {
        const int l15 = t & 15, g = (t >> 4) & 3, p = t >> 6;
        float v[8];
        #pragma unroll
        for (int e = 0; e < 8; ++e) v[e] = w1[(p * 32 + g * 8 + e) * CC + l15];
        uint4 pkv;
        pkv.x = pk2(v[0], v[1]); pkv.y = pk2(v[2], v[3]);
        pkv.z = pk2(v[4], v[5]); pkv.w = pk2(v[6], v[7]);
        *reinterpret_cast<uint4*>(&w1bf[t * 8]) = pkv;
    } else {
        // RNG: pixel j; mask bit (j&63) of group j>>6.  uniform>0.5 <=> bits>=0x80000200
        const unsigned j = (unsigned)(blk - 5) * 256u + (unsigned)t;
        const Key2 r = tf2x32(FK.a, FK.b, 0u, j);
        const unsigned long long m = __ballot((r.a ^ r.b) >= 0x80000200u);
        if ((t & 63) == 0) kmaskbuf[j >> 6] = m;
    }
}

__global__ __launch_bounds__(256, 4)
void ca_fused(const float* __restrict__ x, const short* __restrict__ w0bf,
              const float* __restrict__ b0, const short* __restrict__ w1bf,
              const unsigned long long* __restrict__ kmaskbuf,
              float* __restrict__ out, float* __restrict__ ch1new,
              unsigned char* __restrict__ prelife)
{
    __shared__ short percL[4 * PCL_WAVE2];   // [wave][128 px][36]; per-half aliased as HP
    __shared__ unsigned slotLp[4][2][16];    // lane-63 packed D/S per px-row
    __shared__ unsigned slotRp[4][2][16];    // lane-0  packed D/S per px-row
    __shared__ float    slotLm[4][2];        // lane-63 M per px-row
    __shared__ float    slotRm[4][2];        // lane-0  M per px-row

    const int tid = threadIdx.x;
    const unsigned bid = blockIdx.x;
    const unsigned lb = (bid & 7u) * 256u + (bid >> 3);   // XCD-chunked swizzle (2048 = 8*256)
    const int hpair = lb & 127;
    const unsigned jbase = lb * 512u;        // = (b*HH + 2*hpair)*WW
    const int wave = tid >> 6, lane = tid & 63;
    const int l15 = lane & 15, g = lane >> 4;

    // ---- stochastic masks precomputed in prep: one 64-bit word per (rs, wave) group ----
    const unsigned long long kmask0 = kmaskbuf[lb * 8 + 0 * 4 + wave];
    const unsigned long long kmask1 = kmaskbuf[lb * 8 + 1 * 4 + wave];

    // ---- load 4 rows of own column (R0 = h0-1, R1 = h0, R2 = h1, R3 = h1+1) ----
    const float* pR1 = x + ((size_t)jbase + tid) * CC;
    float4 R0[4], R1[4], R2[4], R3[4];
    #pragma unroll
    for (int q = 0; q < 4; ++q) R1[q] = *reinterpret_cast<const float4*>(pR1 + q * 4);
    #pragma unroll
    for (int q = 0; q < 4; ++q) R2[q] = *reinterpret_cast<const float4*>(pR1 + WW * CC + q * 4);
    if (hpair > 0) {
        #pragma unroll
        for (int q = 0; q < 4; ++q) R0[q] = *reinterpret_cast<const float4*>(pR1 - WW * CC + q * 4);
    } else {
        #pragma unroll
        for (int q = 0; q < 4; ++q) R0[q] = make_float4(0.f, 0.f, 0.f, 0.f);
    }
    if (hpair < 127) {
        #pragma unroll
        for (int q = 0; q < 4; ++q) R3[q] = *reinterpret_cast<const float4*>(pR1 + 2 * WW * CC + q * 4);
    } else {
        #pragma unroll
        for (int q = 0; q < 4; ++q) R3[q] = make_float4(0.f, 0.f, 0.f, 0.f);
    }

    // D/S packed as bf16 pairs (lo=D, hi=S) per channel, per px
    unsigned pkA[16], pkB[16];
    #pragma unroll
    for (int q = 0; q < 4; ++q) {
        const float4 a = R0[q], bb = R1[q], c = R2[q], d = R3[q];
        const float a_[4] = {a.x, a.y, a.z, a.w};
        const float b_[4] = {bb.x, bb.y, bb.z, bb.w};
        const float c_[4] = {c.x, c.y, c.z, c.w};
        const float d_[4] = {d.x, d.y, d.z, d.w};
        #pragma unroll
        for (int e = 0; e < 4; ++e) {
            const int ch = q * 4 + e;
            pkA[ch] = pk2(c_[e] - a_[e], fmaf(2.f, b_[e], a_[e] + c_[e]));   // px1: D,S
            pkB[ch] = pk2(d_[e] - b_[e], fmaf(2.f, c_[e], b_[e] + d_[e]));   // px2: D,S
        }
    }
    const float M1 = fmaxf(fmaxf(R0[0].y, R1[0].y), R2[0].y);
    const float M2 = fmaxf(fmaxf(R1[0].y, R2[0].y), R3[0].y);

    // boundary columns -> LDS slots
    if (lane == 0) {
        #pragma unroll
        for (int c = 0; c < 16; ++c) { slotRp[wave][0][c] = pkA[c]; slotRp[wave][1][c] = pkB[c]; }
        slotRm[wave][0] = M1; slotRm[wave][1] = M2;
    }
    if (lane == 63) {
        #pragma unroll
        for (int c = 0; c < 16; ++c) { slotLp[wave][0][c] = pkA[c]; slotLp[wave][1][c] = pkB[c]; }
        slotLm[wave][0] = M1; slotLm[wave][1] = M2;
    }
    __syncthreads();

    // ---- shuffle-combine (DPP wave shifts) + percL write + prelife, per px ----
    // conv features are UNSCALED (Dl+Dr+2D, Sr-Sl); 0.125 folded into w0bf conv rows.
    #pragma unroll
    for (int rs = 0; rs < 2; ++rs) {
        const unsigned* pk = (rs == 0) ? pkA : pkB;
        float conv[32];
        #pragma unroll
        for (int hf = 0; hf < 2; ++hf) {       // 8 channels at a time (register cap)
            const int c0 = hf * 8;
            unsigned pL[8], pR[8];
            #pragma unroll
            for (int c = 0; c < 8; ++c) {
                pL[c] = dpp_up1(pk[c0 + c]);
                pR[c] = dpp_down1(pk[c0 + c]);
            }
            if (lane == 0) {
                #pragma unroll
                for (int c = 0; c < 8; ++c)
                    pL[c] = (tid == 0) ? 0u : slotLp[wave - 1][rs][c0 + c];
            }
            if (lane == 63) {
                #pragma unroll
                for (int c = 0; c < 8; ++c)
                    pR[c] = (tid == 255) ? 0u : slotRp[wave + 1][rs][c0 + c];
            }
            #pragma unroll
            for (int c = 0; c < 8; ++c) {
                const float Dm = unpk_lo(pk[c0 + c]);
                conv[c0 + c]      = fmaf(2.f, Dm, unpk_lo(pL[c]) + unpk_lo(pR[c])); // k1 (unscaled)
                conv[16 + c0 + c] = unpk_hi(pR[c]) - unpk_hi(pL[c]);                // k2 (unscaled)
            }
        }
        // percL write (wave-local)
        const int base = wave * PCL_WAVE2 + (rs * 64 + lane) * PCL_STRIDE;
        #pragma unroll
        for (int c = 0; c < 8; ++c) {
            uint2 pkv;
            pkv.x = pk2(conv[c*4 + 0], conv[c*4 + 1]);
            pkv.y = pk2(conv[c*4 + 2], conv[c*4 + 3]);
            *reinterpret_cast<uint2*>(&percL[base + c * 4]) = pkv;
        }
        // alive max + prelife
        const float M = (rs == 0) ? M1 : M2;
        float Ml = dpp_up1f(M), Mr = dpp_down1f(M);
        if (lane == 0)  Ml = (tid == 0)   ? -3.0e38f : slotLm[wave - 1][rs];
        if (lane == 63) Mr = (tid == 255) ? -3.0e38f : slotRm[wave + 1][rs];
        const float maxc1 = fmaxf(fmaxf(Ml, M), Mr);
        prelife[jbase + rs * 256 + tid] = (maxc1 > 0.1f) ? (unsigned char)1 : (unsigned char)0;
    }

    const s16x8* w0F = reinterpret_cast<const s16x8*>(w0bf);  // [chunk][lane], 16B/lane
    const s16x8* w1F = reinterpret_cast<const s16x8*>(w1bf);

    // ---- GEMM, one half (64 px = one row chunk) at a time ----
    #pragma unroll
    for (int rs = 0; rs < 2; ++rs) {
        const unsigned pixbase = jbase + rs * 256 + wave * 64;
        const int halfbase = wave * PCL_WAVE2 + rs * 64 * PCL_STRIDE;

        // B-operand fragments: k = [id 0..15 | k1 16..31 | k2 32..47 | pad]
        s16x8 pB0[4], pB1[4];
        #pragma unroll
        for (int mt = 0; mt < 4; ++mt) {
            const int prow = halfbase + (mt * 16 + l15) * PCL_STRIDE;
            V8 f0, f1;
            if (g < 2) {
                const float* xp = &x[(size_t)(pixbase + mt * 16 + l15) * CC + g * 8];
                const float4 va = *reinterpret_cast<const float4*>(xp);
                const float4 vb = *reinterpret_cast<const float4*>(xp + 4);
                f0.u.x = pk2(va.x, va.y); f0.u.y = pk2(va.z, va.w);
                f0.u.z = pk2(vb.x, vb.y); f0.u.w = pk2(vb.z, vb.w);
                f1.h[0] = *reinterpret_cast<const uint2*>(&percL[prow + 16 + g * 8]);
                f1.h[1] = *reinterpret_cast<const uint2*>(&percL[prow + 16 + g * 8 + 4]);
            } else {
                f0.h[0] = *reinterpret_cast<const uint2*>(&percL[prow + (g - 2) * 8]);
                f0.h[1] = *reinterpret_cast<const uint2*>(&percL[prow + (g - 2) * 8 + 4]);
                f1.u = make_uint4(0u, 0u, 0u, 0u);
            }
            pB0[mt] = f0.s;
            pB1[mt] = f1.s;
        }

        __builtin_amdgcn_sched_barrier(0);   // percL reads complete before HP overwrites

        short* HPw = &percL[halfbase];       // [64 px][32 n-of-panel], chunk-XOR swizzle (aliased)
        f32x4 acc2[4];
        #pragma unroll
        for (int mt2 = 0; mt2 < 4; ++mt2) acc2[mt2] = 0.0f;

        __builtin_amdgcn_s_setprio(1);       // favor GEMM-phase waves on the CU scheduler
        #pragma unroll
        for (int p = 0; p < 4; ++p) {
            s16x8 w0f0[2], w0f1[2];
            #pragma unroll
            for (int nt = 0; nt < 2; ++nt) {
                w0f0[nt] = w0F[((p * 2 + nt) * 2 + 0) * 64 + lane];
                w0f1[nt] = w0F[((p * 2 + nt) * 2 + 1) * 64 + lane];
            }
            // bias loads hoisted out of the mt loop (explicit CSE)
            const float4 bvA = *reinterpret_cast<const float4*>(&b0[p*32 + g*4]);
            const float4 bvB = *reinterpret_cast<const float4*>(&b0[p*32 + 16 + g*4]);
            // GEMM1: H^T panel -> relu -> packed b64 HP writes
            #pragma unroll
            for (int mt = 0; mt < 4; ++mt) {
                #pragma unroll
                for (int nt = 0; nt < 2; ++nt) {
                    const float4 bv = (nt == 0) ? bvA : bvB;
                    f32x4 acc = {bv.x, bv.y, bv.z, bv.w};
                    acc = __builtin_amdgcn_mfma_f32_16x16x32_bf16(w0f0[nt], pB0[mt], acc, 0, 0, 0);
                    acc = __builtin_amdgcn_mfma_f32_16x16x32_bf16(w0f1[nt], pB1[mt], acc, 0, 0, 0);
                    uint2 hv;
                    hv.x = pk2(fmaxf(acc[0], 0.f), fmaxf(acc[1], 0.f));
                    hv.y = pk2(fmaxf(acc[2], 0.f), fmaxf(acc[3], 0.f));
                    const int m = mt * 16 + l15;
                    *reinterpret_cast<uint2*>(
                        &HPw[m * 32 + 4 * ((4*nt + g) ^ (l15 & 6))]) = hv;
                }
            }
            // GEMM2 partial: dx^T += w1_panel^T . H^T
            {
                const s16x8 wf = w1F[p * 64 + lane];
                #pragma unroll
                for (int mt2 = 0; mt2 < 4; ++mt2) {
                    const int m = mt2 * 16 + l15;
                    const s16x8 hp = *reinterpret_cast<const s16x8*>(
                        &HPw[m * 32 + 4 * ((2*g) ^ (l15 & 6))]);
                    acc2[mt2] = __builtin_amdgcn_mfma_f32_16x16x32_bf16(wf, hp, acc2[mt2], 0, 0, 0);
                }
            }
        }
        __builtin_amdgcn_s_setprio(0);

        // epilogue for this half: lane holds channels g*4..g*4+3 of px l15+16*mt2
        const unsigned long long kmask = (rs == 0) ? kmask0 : kmask1;
        #pragma unroll
        for (int mt2 = 0; mt2 < 4; ++mt2) {
            const int prel = mt2 * 16 + l15;
            const unsigned pj = pixbase + prel;
            const float kv = ((kmask >> prel) & 1ull) ? 1.0f : 0.0f;
            const float4 x4 = *reinterpret_cast<const float4*>(&x[(size_t)pj * CC + g * 4]);
            float4 v;
            v.x = x4.x + acc2[mt2][0] * kv;
            v.y = x4.y + acc2[mt2][1] * kv;
            v.z = x4.z + acc2[mt2][2] * kv;
            v.w = x4.w + acc2[mt2][3] * kv;
            *reinterpret_cast<float4*>(&out[(size_t)pj * CC + g * 4]) = v;
            if (g == 0) ch1new[pj] = v.y;   // channel 1
        }
    }
}

__global__ __launch_bounds__(256)
void ca_step2(float* __restrict__ out, const float* __restrict__ ch1new,
              const unsigned char* __restrict__ prelife)
{
    const int tid = threadIdx.x;
    const int lane = tid & 63;           // 64 lanes x 4 pixels = 256 w
    const int rowi = tid >> 6;           // 4 rows per block
    const unsigned bid = blockIdx.x;     // 1024 blocks
    const int hq = bid & 63, b = bid >> 6;
    const int h = hq * 4 + rowi;
    const unsigned rowbase = ((unsigned)(b * HH + h)) * WW;
    const int w0 = lane * 4;

    float4 vc = *reinterpret_cast<const float4*>(&ch1new[rowbase + w0]);
    float m0 = vc.x, m1 = vc.y, m2 = vc.z, m3 = vc.w;
    if (h > 0) {
        float4 vu = *reinterpret_cast<const float4*>(&ch1new[rowbase - WW + w0]);
        m0 = fmaxf(m0, vu.x); m1 = fmaxf(m1, vu.y); m2 = fmaxf(m2, vu.z); m3 = fmaxf(m3, vu.w);
    }
    if (h < HH - 1) {
        float4 vd = *reinterpret_cast<const float4*>(&ch1new[rowbase + WW + w0]);
        m0 = fmaxf(m0, vd.x); m1 = fmaxf(m1, vd.y); m2 = fmaxf(m2, vd.z); m3 = fmaxf(m3, vd.w);
    }
    float left  = __shfl_up(m3, 1);   if (lane == 0)  left  = -3.0e38f;
    float right = __shfl_down(m0, 1); if (lane == 63) right = -3.0e38f;

    float mm[4];
    mm[0] = fmaxf(fmaxf(left, m0), m1);
    mm[1] = fmaxf(fmaxf(m0, m1), m2);
    mm[2] = fmaxf(fmaxf(m1, m2), m3);
    mm[3] = fmaxf(fmaxf(m2, m3), right);

    const uchar4 pl = *reinterpret_cast<const uchar4*>(&prelife[rowbase + w0]);
    const unsigned char pla[4] = {pl.x, pl.y, pl.z, pl.w};
    bool dead[4];
    bool anydead = false;
    #pragma unroll
    for (int i = 0; i < 4; ++i) {
        dead[i] = !((pla[i] != 0) && (mm[i] > 0.1f));
        anydead |= dead[i];
    }
    // whole-wave early-out: with typical data nearly all pixels are alive
    if (__ballot(anydead) == 0ull) return;
    #pragma unroll
    for (int i = 0; i < 4; ++i) {
        if (dead[i]) {
            const float4 z = make_float4(0.f, 0.f, 0.f, 0.f);
            float4* o = reinterpret_cast<float4*>(out + (size_t)(rowbase + w0 + i) * CC);
            o[0] = z; o[1] = z; o[2] = z; o[3] = z;
        }
    }
}

extern "C" void kernel_launch(void* const* d_in, const int* in_sizes, int n_in,
                              void* d_out, int out_size, void* d_ws, size_t ws_size,
                              hipStream_t stream) {
    const float* x  = (const float*)d_in[0];
    const float* w0 = (const float*)d_in[1];
    const float* b0 = (const float*)d_in[2];
    const float* w1 = (const float*)d_in[3];
    float* out = (float*)d_out;

    float* ch1new = (float*)d_ws;                                       // NPIX floats (4 MB)
    unsigned char* prelife = (unsigned char*)d_ws + (size_t)NPIX * 4;   // NPIX bytes (1 MB)
    short* w0bf = (short*)((char*)d_ws + 5242880);                      // 16 KB
    short* w1bf = (short*)((char*)d_ws + 5242880 + 16384);              // 4 KB
    unsigned long long* kmaskbuf =
        (unsigned long long*)((char*)d_ws + 5242880 + 20480);           // 128 KB (16384 x 8 B)

    ca_prep<<<dim3(5 + NPIX / 256), dim3(256), 0, stream>>>(w0, w1, w0bf, w1bf, kmaskbuf);
    ca_fused<<<dim3(NBLK2), dim3(256), 0, stream>>>(x, w0bf, b0, w1bf, kmaskbuf, out, ch1new, prelife);
    ca_step2<<<dim3(NPIX / 1024), dim3(256), 0, stream>>>(out, ch1new, prelife);
}